// Round 4
// baseline (27.635 us; speedup 1.0000x reference)
//
#include <hip/hip_runtime.h>

// CubPL2d: persistence landscape top-2 over pairs.
// x: [B=128, C=64, H=64, W=64] f32; birth/death/pair_dim: [B, C, P=128] i32.
// out: [B, C, D=2, K=2, T=32] f32.
//
// One wave64 per TWO (b,c) slices (R3 change). Lane l owns output slot
// (d = l>>5, t = l&31) for both slices.
// Rationale: R2 showed the inner scan is not the limiter; the serial
// idx->gather->scan dependency chain with 8192 lockstep waves leaves
// correlated stall bubbles. Interleaving two slices per wave doubles
// memory-level parallelism (6 idx loads then 8 gathers in flight) and
// roughly halves per-slice exposed latency.
//
// Per slice: compacted per-dim LDS tables (position = ballot popcount
// prefix; order irrelevant for top-2), sentinel entry absorbs the odd-tail
// b128 over-read, dim mask folded into data. No __syncthreads (tables are
// wave-private); a wave-local s_waitcnt lgkmcnt(0) orders write->read.

constexpr int P = 128;
constexpr float T_MIN = 0.03f;
constexpr float T_MAX = 0.34f;
constexpr float BIG = 1e30f;

__global__ __launch_bounds__(256) void pl_topk_kernel(
    const float* __restrict__ x,
    const int* __restrict__ birth_idx,
    const int* __restrict__ death_idx,
    const int* __restrict__ pair_dim,
    float* __restrict__ out)
{
    // [wave][slice][dim][entry] -> (birth, death); 130 = 128 + sentinel +
    // 16B-alignment (130*8 = 1040 = 65*16). 16.25 KB per 256-thread block.
    __shared__ float2 tab[4][2][2][130];

    const int lane = threadIdx.x & 63;
    const int w = threadIdx.x >> 6;
    const int gid = blockIdx.x * 4 + w;
    const int wid0 = 2 * gid;          // first slice (b*C + c)
    // wid1 = wid0 + 1

    const int d_lane = lane >> 5;
    const int t_idx = lane & 31;
    const float t = T_MIN + (T_MAX - T_MIN) * (float)t_idx * (1.0f / 31.0f);

    // ---- issue ALL index loads for both slices (6 dwordx2 in flight) ----
    const long pb0 = (long)wid0 * P;
    const long pb1 = pb0 + P;
    const int2 biA = *reinterpret_cast<const int2*>(&birth_idx[pb0 + 2 * lane]);
    const int2 biB = *reinterpret_cast<const int2*>(&birth_idx[pb1 + 2 * lane]);
    const int2 diA = *reinterpret_cast<const int2*>(&death_idx[pb0 + 2 * lane]);
    const int2 diB = *reinterpret_cast<const int2*>(&death_idx[pb1 + 2 * lane]);
    const int2 dmA = *reinterpret_cast<const int2*>(&pair_dim[pb0 + 2 * lane]);
    const int2 dmB = *reinterpret_cast<const int2*>(&pair_dim[pb1 + 2 * lane]);

    // ---- issue ALL 8 gathers ----
    const long xb0 = (long)wid0 * 4096;   // H*W
    const long xb1 = xb0 + 4096;
    const float vA_b0 = x[xb0 + biA.x];
    const float vA_b1 = x[xb0 + biA.y];
    const float vA_d0 = x[xb0 + diA.x];
    const float vA_d1 = x[xb0 + diA.y];
    const float vB_b0 = x[xb1 + biB.x];
    const float vB_b1 = x[xb1 + biB.y];
    const float vB_d0 = x[xb1 + diB.x];
    const float vB_d1 = x[xb1 + diB.y];

    // ---- compaction positions via ballot popcount prefix (both slices) ----
    const unsigned long long below = (lane == 63) ? ~0ull >> 1
                                                  : (1ull << lane) - 1ull;
    // slice A
    const unsigned long long aA1 = __ballot(dmA.x == 1);
    const unsigned long long bA1 = __ballot(dmA.y == 1);
    const int nA_a0 = __popcll(~aA1);
    const int nA_a1 = 64 - nA_a0;
    const int nA0 = nA_a0 + __popcll(~bA1);
    const int nA1 = P - nA0;
    const int posAa = __popcll((dmA.x ? aA1 : ~aA1) & below);
    const int posAb = (dmA.y ? nA_a1 : nA_a0) + __popcll((dmA.y ? bA1 : ~bA1) & below);
    // slice B
    const unsigned long long aB1 = __ballot(dmB.x == 1);
    const unsigned long long bB1 = __ballot(dmB.y == 1);
    const int nB_a0 = __popcll(~aB1);
    const int nB_a1 = 64 - nB_a0;
    const int nB0 = nB_a0 + __popcll(~bB1);
    const int nB1 = P - nB0;
    const int posBa = __popcll((dmB.x ? aB1 : ~aB1) & below);
    const int posBb = (dmB.y ? nB_a1 : nB_a0) + __popcll((dmB.y ? bB1 : ~bB1) & below);

    // ---- build tables ----
    tab[w][0][dmA.x][posAa] = make_float2(vA_b0, vA_d0);
    tab[w][0][dmA.y][posAb] = make_float2(vA_b1, vA_d1);
    tab[w][1][dmB.x][posBa] = make_float2(vB_b0, vB_d0);
    tab[w][1][dmB.y][posBb] = make_float2(vB_b1, vB_d1);
    if (lane < 4) {
        const int s = lane >> 1, d = lane & 1;
        const int n = s ? (d ? nB1 : nB0) : (d ? nA1 : nA0);
        tab[w][s][d][n] = make_float2(BIG, -BIG);   // odd-tail sentinel
    }

    // wave-local ordering only: this wave's ds_writes before its ds_reads
    asm volatile("s_waitcnt lgkmcnt(0)" ::: "memory");

    // ---- top-2 scans ----
    const int nMine0 = d_lane ? nA1 : nA0;
    const int nMine1 = d_lane ? nB1 : nB0;

    float m1a = 0.0f, m2a = 0.0f;
    {
        const float2* tp = &tab[w][0][d_lane][0];
        #pragma unroll 2
        for (int p = 0; p < nMine0; p += 2) {
            const float4 e = *reinterpret_cast<const float4*>(&tp[p]);
            const float v0 = fminf(t - e.x, e.y - t);
            const float v1 = fminf(t - e.z, e.w - t);
            m2a = fmaxf(m2a, fminf(m1a, v0));
            m1a = fmaxf(m1a, v0);
            m2a = fmaxf(m2a, fminf(m1a, v1));
            m1a = fmaxf(m1a, v1);
        }
    }
    float m1b = 0.0f, m2b = 0.0f;
    {
        const float2* tp = &tab[w][1][d_lane][0];
        #pragma unroll 2
        for (int p = 0; p < nMine1; p += 2) {
            const float4 e = *reinterpret_cast<const float4*>(&tp[p]);
            const float v0 = fminf(t - e.x, e.y - t);
            const float v1 = fminf(t - e.z, e.w - t);
            m2b = fmaxf(m2b, fminf(m1b, v0));
            m1b = fmaxf(m1b, v0);
            m2b = fmaxf(m2b, fminf(m1b, v1));
            m1b = fmaxf(m1b, v1);
        }
    }

    // ---- write out: per (b,c) layout is [D, K, T] = 128 floats ----
    float* o0 = out + (long)wid0 * 128;
    o0[d_lane * 64 + t_idx] = m1a;
    o0[d_lane * 64 + 32 + t_idx] = m2a;
    float* o1 = o0 + 128;
    o1[d_lane * 64 + t_idx] = m1b;
    o1[d_lane * 64 + 32 + t_idx] = m2b;
}

extern "C" void kernel_launch(void* const* d_in, const int* in_sizes, int n_in,
                              void* d_out, int out_size, void* d_ws, size_t ws_size,
                              hipStream_t stream) {
    const float* x = (const float*)d_in[0];
    const int* birth_idx = (const int*)d_in[1];
    const int* death_idx = (const int*)d_in[2];
    const int* pair_dim = (const int*)d_in[3];
    float* out = (float*)d_out;

    // 8192 (b,c) slices, two per wave, 4 waves per 256-thread block.
    dim3 grid(1024), block(256);
    hipLaunchKernelGGL(pl_topk_kernel, grid, block, 0, stream,
                       x, birth_idx, death_idx, pair_dim, out);
}